// Round 13
// baseline (161.339 us; speedup 1.0000x reference)
//
#include <hip/hip_runtime.h>

// GraphSAGE 2-layer forward: ELL-gather aggregation + bf16 MFMA GEMMs.
// Round 12: un-merge fill from prep (merge caused 8x writeback amplification:
// streaming f2b traffic evicted the ELL rows' L2 lines between the ~12
// scattered u16 writes each row receives -> WRITE_SIZE 46MB vs 18MB logical).
// Round-8 structure + hipMemsetAsync(cnt).

typedef __attribute__((ext_vector_type(8))) short short8;
typedef __attribute__((ext_vector_type(4))) short short4v;
typedef __attribute__((ext_vector_type(4))) float f32x4;

constexpr int ELL = 48;   // max degree capacity; P(Poisson(12) >= 48) ~ 1e-13

__device__ inline unsigned short f2b(float f) {           // fp32 -> bf16 RNE
    union { float f; unsigned int u; } v; v.f = f;
    unsigned int u = v.u + 0x7FFFu + ((v.u >> 16) & 1u);
    return (unsigned short)(u >> 16);
}
__device__ inline float b2f(unsigned short h) {
    union { unsigned int u; float f; } v; v.u = ((unsigned int)h) << 16;
    return v.f;
}

// prep: [0,nbF2b) x->bf16 | [nbF2b,+nbW) weight transpose->bf16
__global__ __launch_bounds__(256) void prep_k(
    const float* __restrict__ x,
    const float* __restrict__ Wl1, const float* __restrict__ Wr1,
    const float* __restrict__ Wl2, const float* __restrict__ Wr2,
    unsigned short* __restrict__ x_bf,
    unsigned short* __restrict__ Wt1, unsigned short* __restrict__ Wt2,
    long n4, int nbF2b)
{
    int b = blockIdx.x;
    const int tid = threadIdx.x;
    if (b < nbF2b) {                                     // x -> bf16
        long i = (long)b * 256 + tid;
        if (i < n4) {
            float4 v = *(const float4*)(x + i * 4);
            short4v o;
            o[0] = (short)f2b(v.x); o[1] = (short)f2b(v.y);
            o[2] = (short)f2b(v.z); o[3] = (short)f2b(v.w);
            *(short4v*)(x_bf + i * 4) = o;
        }
        return;
    }
    b -= nbF2b;
    {                                                    // weight transpose
        int y = b >> 7;                                  // 4 sections x 128 blocks
        int idx = (b & 127) * 256 + tid;                 // < 32768
        const float* srcp = (y == 0) ? Wl1 : (y == 1) ? Wr1 : (y == 2) ? Wl2 : Wr2;
        unsigned short* dstp = (y < 2) ? (Wt1 + (size_t)y * 32768)
                                       : (Wt2 + (size_t)(y - 2) * 32768);
        int K1 = (y < 2) ? 128 : 256;
        int H  = (y < 2) ? 256 : 128;
        int n = idx / K1, k = idx % K1;
        dstp[idx] = f2b(srcp[(size_t)k * H + n]);
    }
}

// ELL fill: nbr[dst*ELL + cursor++] = (u16)src  (standalone: keeps its
// 4.8MB row working set L2-resident across the ~12 writes per row)
__global__ __launch_bounds__(256) void fill_ell_k(
    const int* __restrict__ src, const int* __restrict__ dst,
    int* __restrict__ cnt, unsigned short* __restrict__ nbr, int E)
{
    int e = blockIdx.x * blockDim.x + threadIdx.x;
    if (e >= E) return;
    int d = dst[e];
    int p = atomicAdd(&cnt[d], 1);
    if (p < ELL) nbr[(size_t)d * ELL + p] = (unsigned short)src[e];
}

// fp32 accumulate of bf16 rows over an ELL row; 4-deep batches.
template<int C>
__device__ inline void ell_row_sum(
    const unsigned short* __restrict__ feat,
    const unsigned short* __restrict__ row,
    int deg, int g, float (&acc)[8])
{
    int i = 0;
    for (; i + 4 <= deg; i += 4) {
        ushort4 s4 = *(const ushort4*)(row + i);
        short8 v0 = *(const short8*)(feat + (size_t)s4.x * C + g * 8);
        short8 v1 = *(const short8*)(feat + (size_t)s4.y * C + g * 8);
        short8 v2 = *(const short8*)(feat + (size_t)s4.z * C + g * 8);
        short8 v3 = *(const short8*)(feat + (size_t)s4.w * C + g * 8);
#pragma unroll
        for (int j = 0; j < 8; ++j)
            acc[j] += (b2f((unsigned short)v0[j]) + b2f((unsigned short)v1[j]))
                    + (b2f((unsigned short)v2[j]) + b2f((unsigned short)v3[j]));
    }
    for (; i < deg; ++i) {
        int s = row[i];
        short8 v0 = *(const short8*)(feat + (size_t)s * C + g * 8);
#pragma unroll
        for (int j = 0; j < 8; ++j) acc[j] += b2f((unsigned short)v0[j]);
    }
}

// mean[node] = (1/deg) * sum feat[nbr[i]]; bf16 in/out.
template<int C>
__global__ __launch_bounds__(256) void gather_mean_k(
    const unsigned short* __restrict__ feat,
    const int* __restrict__ cnt,
    const unsigned short* __restrict__ nbr,
    unsigned short* __restrict__ mean,
    int N)
{
    constexpr int GPN = C / 8;
    constexpr int NPB = 256 / GPN;
    int node = blockIdx.x * NPB + threadIdx.x / GPN;
    int g = threadIdx.x % GPN;
    if (node >= N) return;
    int deg = min(cnt[node], ELL);
    float acc[8] = {};
    ell_row_sum<C>(feat, nbr + (size_t)node * ELL, deg, g, acc);
    float sc = 1.0f / (float)max(deg, 1);
    short8 o;
#pragma unroll
    for (int j = 0; j < 8; ++j) o[j] = (short)f2b(acc[j] * sc);
    *(short8*)(mean + (size_t)node * C + g * 8) = o;
}

// out[node] = z[node] + (1/deg) * sum y[nbr[i]]   (f32 out; z has bias folded)
template<int C>
__global__ __launch_bounds__(256) void gather_add_out_k(
    const unsigned short* __restrict__ y,
    const unsigned short* __restrict__ z,
    const int* __restrict__ cnt,
    const unsigned short* __restrict__ nbr,
    float* __restrict__ out,
    int N)
{
    constexpr int GPN = C / 8;
    constexpr int NPB = 256 / GPN;
    int node = blockIdx.x * NPB + threadIdx.x / GPN;
    int g = threadIdx.x % GPN;
    if (node >= N) return;
    int deg = min(cnt[node], ELL);
    float acc[8] = {};
    ell_row_sum<C>(y, nbr + (size_t)node * ELL, deg, g, acc);
    float sc = 1.0f / (float)max(deg, 1);
    short8 zv = *(const short8*)(z + (size_t)node * C + g * 8);
    float* o = out + (size_t)node * C + g * 8;
    float4 r0, r1;
    r0.x = b2f((unsigned short)zv[0]) + acc[0] * sc;
    r0.y = b2f((unsigned short)zv[1]) + acc[1] * sc;
    r0.z = b2f((unsigned short)zv[2]) + acc[2] * sc;
    r0.w = b2f((unsigned short)zv[3]) + acc[3] * sc;
    r1.x = b2f((unsigned short)zv[4]) + acc[4] * sc;
    r1.y = b2f((unsigned short)zv[5]) + acc[5] * sc;
    r1.z = b2f((unsigned short)zv[6]) + acc[6] * sc;
    r1.w = b2f((unsigned short)zv[7]) + acc[7] * sc;
    *(float4*)o = r0;
    *(float4*)(o + 4) = r1;
}

// Layer-1 fused MFMA GEMM: h = relu( mean@Wt[0] + x@Wt[1] + b1 )
template<int HOUT>
__global__ __launch_bounds__(256) void sage_mfma_l1_k(
    const unsigned short* __restrict__ A0,
    const unsigned short* __restrict__ A1,
    const unsigned short* __restrict__ Wt,
    const float* __restrict__ bias,
    unsigned short* __restrict__ out,
    int N)
{
    constexpr int BM = 128, BN = 64, NF = BN / 16, K1 = 128;
    __shared__ char lds[BN * 256 * 2];           // 32 KB

    const int tid = threadIdx.x;
    const int lane = tid & 63;
    const int w = tid >> 6;
    const int l15 = lane & 15;
    const int lhi = lane >> 4;
    const int bm = blockIdx.x * BM;
    const int bn = blockIdx.y * BN;

    short8 a[2][8];
#pragma unroll
    for (int mf = 0; mf < 2; ++mf) {
        int row = bm + w * 32 + mf * 16 + l15;
        if (row >= N) row = N - 1;
#pragma unroll
        for (int ki = 0; ki < 8; ++ki) {
            const unsigned short* base = (ki < 4) ? A0 : A1;
            a[mf][ki] = *(const short8*)(base + (size_t)row * K1 +
                                         (ki & 3) * 32 + lhi * 8);
        }
    }

#pragma unroll
    for (int i = 0; i < 8; ++i) {
        int u = i * 256 + tid;
        int row = u >> 5, k16 = u & 31;
        int c = k16 >> 4;
        const unsigned short* srcp = Wt + (size_t)c * HOUT * 128 +
                                     (size_t)(bn + row) * 128 + (k16 & 15) * 8;
        short8 v = *(const short8*)srcp;
        *(short8*)(lds + row * 512 + ((k16 ^ (row & 7)) << 4)) = v;
    }
    __syncthreads();

    f32x4 acc[2][NF];
#pragma unroll
    for (int mf = 0; mf < 2; ++mf)
#pragma unroll
        for (int nf = 0; nf < NF; ++nf)
            acc[mf][nf] = (f32x4){0.f, 0.f, 0.f, 0.f};

#pragma unroll
    for (int ki = 0; ki < 8; ++ki) {
        const int k16b = ki * 4 + lhi;
#pragma unroll
        for (int nf = 0; nf < NF; ++nf) {
            int row = nf * 16 + l15;
            short8 b = *(const short8*)(lds + row * 512 +
                                        ((k16b ^ (row & 7)) << 4));
            acc[0][nf] = __builtin_amdgcn_mfma_f32_16x16x32_bf16(a[0][ki], b, acc[0][nf], 0, 0, 0);
            acc[1][nf] = __builtin_amdgcn_mfma_f32_16x16x32_bf16(a[1][ki], b, acc[1][nf], 0, 0, 0);
        }
    }

#pragma unroll
    for (int nf = 0; nf < NF; ++nf) {
        int col = bn + nf * 16 + l15;
        float bv = bias[col];
#pragma unroll
        for (int mf = 0; mf < 2; ++mf) {
#pragma unroll
            for (int r = 0; r < 4; ++r) {
                int row = bm + w * 32 + mf * 16 + lhi * 4 + r;
                if (row < N) {
                    float v = fmaxf(acc[mf][nf][r] + bv, 0.f);
                    out[(size_t)row * HOUT + col] = f2b(v);
                }
            }
        }
    }
}

// Layer-2 dual MFMA GEMM: y = A@W0, z = A@W1 + b2 (both bf16 out).
template<int HOUT>
__global__ __launch_bounds__(256) void dual_mfma_k(
    const unsigned short* __restrict__ A,
    const unsigned short* __restrict__ W0,
    const unsigned short* __restrict__ W1,
    const float* __restrict__ bias,
    unsigned short* __restrict__ y,
    unsigned short* __restrict__ z,
    int N)
{
    constexpr int BM = 128, BN = 32, NF = BN / 16, K1 = 256;
    __shared__ char lds[2 * BN * K1 * 2];        // 32 KB

    const int tid = threadIdx.x;
    const int lane = tid & 63;
    const int w = tid >> 6;
    const int l15 = lane & 15;
    const int lhi = lane >> 4;
    const int bm = blockIdx.x * BM;
    const int bn = blockIdx.y * BN;

    short8 a[2][8];
#pragma unroll
    for (int mf = 0; mf < 2; ++mf) {
        int row = bm + w * 32 + mf * 16 + l15;
        if (row >= N) row = N - 1;
        const unsigned short* ar = A + (size_t)row * K1;
#pragma unroll
        for (int ki = 0; ki < 8; ++ki)
            a[mf][ki] = *(const short8*)(ar + ki * 32 + lhi * 8);
    }

#pragma unroll
    for (int i = 0; i < 8; ++i) {
        int u = i * 256 + tid;                   // < 2048
        int slice = u >> 10;
        int rem = u & 1023;
        int row = rem >> 5, k16 = rem & 31;
        const unsigned short* srcp = (slice ? W1 : W0) +
                                     (size_t)(bn + row) * K1 + k16 * 8;
        short8 v = *(const short8*)srcp;
        *(short8*)(lds + slice * 16384 + row * 512 +
                   ((k16 ^ (row & 7)) << 4)) = v;
    }
    __syncthreads();

    f32x4 accY[2][NF], accZ[2][NF];
#pragma unroll
    for (int mf = 0; mf < 2; ++mf)
#pragma unroll
        for (int nf = 0; nf < NF; ++nf) {
            accY[mf][nf] = (f32x4){0.f, 0.f, 0.f, 0.f};
            accZ[mf][nf] = (f32x4){0.f, 0.f, 0.f, 0.f};
        }

#pragma unroll
    for (int ki = 0; ki < 8; ++ki) {
        const int k16b = ki * 4 + lhi;
#pragma unroll
        for (int nf = 0; nf < NF; ++nf) {
            int row = nf * 16 + l15;
            int off = row * 512 + ((k16b ^ (row & 7)) << 4);
            short8 b0 = *(const short8*)(lds + off);
            short8 b1 = *(const short8*)(lds + 16384 + off);
            accY[0][nf] = __builtin_amdgcn_mfma_f32_16x16x32_bf16(a[0][ki], b0, accY[0][nf], 0, 0, 0);
            accY[1][nf] = __builtin_amdgcn_mfma_f32_16x16x32_bf16(a[1][ki], b0, accY[1][nf], 0, 0, 0);
            accZ[0][nf] = __builtin_amdgcn_mfma_f32_16x16x32_bf16(a[0][ki], b1, accZ[0][nf], 0, 0, 0);
            accZ[1][nf] = __builtin_amdgcn_mfma_f32_16x16x32_bf16(a[1][ki], b1, accZ[1][nf], 0, 0, 0);
        }
    }

#pragma unroll
    for (int nf = 0; nf < NF; ++nf) {
        int col = bn + nf * 16 + l15;
        float bv = bias[col];
#pragma unroll
        for (int mf = 0; mf < 2; ++mf) {
#pragma unroll
            for (int r = 0; r < 4; ++r) {
                int row = bm + w * 32 + mf * 16 + lhi * 4 + r;
                if (row < N) {
                    y[(size_t)row * HOUT + col] = f2b(accY[mf][nf][r]);
                    z[(size_t)row * HOUT + col] = f2b(accZ[mf][nf][r] + bv);
                }
            }
        }
    }
}

extern "C" void kernel_launch(void* const* d_in, const int* in_sizes, int n_in,
                              void* d_out, int out_size, void* d_ws, size_t ws_size,
                              hipStream_t stream) {
    const float* x   = (const float*)d_in[0];
    const int*   ei  = (const int*)d_in[1];
    const float* Wl1 = (const float*)d_in[2];
    const float* Wr1 = (const float*)d_in[3];
    const float* b1  = (const float*)d_in[4];
    const float* Wl2 = (const float*)d_in[5];
    const float* Wr2 = (const float*)d_in[6];
    const float* b2  = (const float*)d_in[7];
    float* out = (float*)d_out;

    const int N = in_sizes[0] / 128;   // 50000
    const int E = in_sizes[1] / 2;     // 600000
    const int* src = ei;
    const int* dst = ei + E;

    // ws layout:
    //   S [N*256 u16]: layer1 mean_bf | layer2 {y_bf, z_bf} (each N*128)
    //   | h_bf [N*256 u16] | x_bf [N*128 u16]
    //   | Wt1 [2*256*128 u16] | Wt2 [2*128*256 u16]
    //   | cnt [N i32] | nbr [N*ELL u16]
    char* ws = (char*)d_ws;
    unsigned short* S       = (unsigned short*)ws;
    unsigned short* mean_bf = S;
    unsigned short* y_bf    = S;
    unsigned short* z_bf    = S + (size_t)N * 128;
    unsigned short* h_bf    = S + (size_t)N * 256;
    unsigned short* x_bf    = h_bf + (size_t)N * 256;
    unsigned short* Wt1     = x_bf + (size_t)N * 128;
    unsigned short* Wt2     = Wt1 + 2 * 256 * 128;
    int*            cnt     = (int*)(Wt2 + 2 * 128 * 256);
    unsigned short* nbr     = (unsigned short*)(cnt + N);

    const int gx = (N + 127) / 128;    // 391

    // ---- cnt = 0 (stream-ordered, graph-capturable) ----
    hipMemsetAsync(cnt, 0, (size_t)N * sizeof(int), stream);

    // ---- prep: x->bf16 + weight transpose ----
    long n4 = (long)N * 128 / 4;
    const int nbF2b = (int)((n4 + 255) / 256);       // 6250
    const int nbW   = 512;
    prep_k<<<nbF2b + nbW, 256, 0, stream>>>(
        x, Wl1, Wr1, Wl2, Wr2, x_bf, Wt1, Wt2, n4, nbF2b);

    // ---- ELL adjacency fill (standalone: L2-resident rows) ----
    fill_ell_k<<<(E + 255) / 256, 256, 0, stream>>>(src, dst, cnt, nbr, E);

    // ---- layer 1: mean(x) -> h = relu([mean|x] @ [Wl1;Wr1] + b1) ----
    gather_mean_k<128><<<(N + 15) / 16, 256, 0, stream>>>(
        x_bf, cnt, nbr, mean_bf, N);
    sage_mfma_l1_k<256><<<dim3(gx, 4), 256, 0, stream>>>(
        mean_bf, x_bf, Wt1, b1, h_bf, N);

    // ---- layer 2: {y,z} = h @ {Wl2, Wr2+b2} ; out = z + mean(y) ----
    dual_mfma_k<128><<<dim3(gx, 4), 256, 0, stream>>>(
        h_bf, Wt2, Wt2 + 128 * 256, b2, y_bf, z_bf, N);
    gather_add_out_k<128><<<(N + 15) / 16, 256, 0, stream>>>(
        y_bf, z_bf, cnt, nbr, out, N);
}

// Round 14
// 154.177 us; speedup vs baseline: 1.0465x; 1.0465x over previous
//
#include <hip/hip_runtime.h>

// GraphSAGE 2-layer forward: ELL-gather aggregation + bf16 MFMA GEMMs.
// Round 13: exact revert to the round-8 structure (measured best, 154us).
// - prep_k: x->bf16 + weight transpose + cnt zeroing in one grid
// - fill_ell_k standalone (L2-resident ELL rows; merging regressed in r12)
// - no hipMemsetAsync (its fill dispatch cost ~4-7us in r13)
// - 4-deep gather unroll (8-deep was neutral in r9/r10 -> throughput-bound)

typedef __attribute__((ext_vector_type(8))) short short8;
typedef __attribute__((ext_vector_type(4))) short short4v;
typedef __attribute__((ext_vector_type(4))) float f32x4;

constexpr int ELL = 48;   // max degree capacity; P(Poisson(12) >= 48) ~ 1e-13

__device__ inline unsigned short f2b(float f) {           // fp32 -> bf16 RNE
    union { float f; unsigned int u; } v; v.f = f;
    unsigned int u = v.u + 0x7FFFu + ((v.u >> 16) & 1u);
    return (unsigned short)(u >> 16);
}
__device__ inline float b2f(unsigned short h) {
    union { unsigned int u; float f; } v; v.u = ((unsigned int)h) << 16;
    return v.f;
}

// prep: [0,nbF2b) x->bf16 | [nbF2b,+nbW) weight transpose->bf16 | rest: zero cnt
__global__ __launch_bounds__(256) void prep_k(
    const float* __restrict__ x,
    const float* __restrict__ Wl1, const float* __restrict__ Wr1,
    const float* __restrict__ Wl2, const float* __restrict__ Wr2,
    unsigned short* __restrict__ x_bf,
    unsigned short* __restrict__ Wt1, unsigned short* __restrict__ Wt2,
    int* __restrict__ cnt,
    long n4, int N, int nbF2b, int nbW)
{
    int b = blockIdx.x;
    const int tid = threadIdx.x;
    if (b < nbF2b) {
        long i = (long)b * 256 + tid;
        if (i < n4) {
            float4 v = *(const float4*)(x + i * 4);
            short4v o;
            o[0] = (short)f2b(v.x); o[1] = (short)f2b(v.y);
            o[2] = (short)f2b(v.z); o[3] = (short)f2b(v.w);
            *(short4v*)(x_bf + i * 4) = o;
        }
        return;
    }
    b -= nbF2b;
    if (b < nbW) {
        int y = b >> 7;                                  // 4 sections x 128 blocks
        int idx = (b & 127) * 256 + tid;                 // < 32768
        const float* src = (y == 0) ? Wl1 : (y == 1) ? Wr1 : (y == 2) ? Wl2 : Wr2;
        unsigned short* dst = (y < 2) ? (Wt1 + (size_t)y * 32768)
                                      : (Wt2 + (size_t)(y - 2) * 32768);
        int K1 = (y < 2) ? 128 : 256;
        int H  = (y < 2) ? 256 : 128;
        int n = idx / K1, k = idx % K1;
        dst[idx] = f2b(src[(size_t)k * H + n]);
        return;
    }
    b -= nbW;
    int i = b * 256 + tid;                               // int4 index
    if (i < N / 4) ((int4*)cnt)[i] = (int4){0, 0, 0, 0};
}

// ELL fill: nbr[dst*ELL + cursor++] = (u16)src
__global__ __launch_bounds__(256) void fill_ell_k(
    const int* __restrict__ src, const int* __restrict__ dst,
    int* __restrict__ cnt, unsigned short* __restrict__ nbr, int E)
{
    int e = blockIdx.x * blockDim.x + threadIdx.x;
    if (e >= E) return;
    int d = dst[e];
    int p = atomicAdd(&cnt[d], 1);
    if (p < ELL) nbr[(size_t)d * ELL + p] = (unsigned short)src[e];
}

// fp32 accumulate of bf16 rows over an ELL row; 4 ids per ushort4 load.
template<int C>
__device__ inline void ell_row_sum(
    const unsigned short* __restrict__ feat,
    const unsigned short* __restrict__ row,
    int deg, int g, float (&acc)[8])
{
    int i = 0;
    for (; i + 4 <= deg; i += 4) {
        ushort4 s4 = *(const ushort4*)(row + i);
        short8 v0 = *(const short8*)(feat + (size_t)s4.x * C + g * 8);
        short8 v1 = *(const short8*)(feat + (size_t)s4.y * C + g * 8);
        short8 v2 = *(const short8*)(feat + (size_t)s4.z * C + g * 8);
        short8 v3 = *(const short8*)(feat + (size_t)s4.w * C + g * 8);
#pragma unroll
        for (int j = 0; j < 8; ++j)
            acc[j] += (b2f((unsigned short)v0[j]) + b2f((unsigned short)v1[j]))
                    + (b2f((unsigned short)v2[j]) + b2f((unsigned short)v3[j]));
    }
    for (; i < deg; ++i) {
        int s = row[i];
        short8 v0 = *(const short8*)(feat + (size_t)s * C + g * 8);
#pragma unroll
        for (int j = 0; j < 8; ++j) acc[j] += b2f((unsigned short)v0[j]);
    }
}

// mean[node] = (1/deg) * sum feat[nbr[i]]; bf16 in/out.
template<int C>
__global__ __launch_bounds__(256) void gather_mean_k(
    const unsigned short* __restrict__ feat,
    const int* __restrict__ cnt,
    const unsigned short* __restrict__ nbr,
    unsigned short* __restrict__ mean,
    int N)
{
    constexpr int GPN = C / 8;
    constexpr int NPB = 256 / GPN;
    int node = blockIdx.x * NPB + threadIdx.x / GPN;
    int g = threadIdx.x % GPN;
    if (node >= N) return;
    int deg = min(cnt[node], ELL);
    float acc[8] = {};
    ell_row_sum<C>(feat, nbr + (size_t)node * ELL, deg, g, acc);
    float sc = 1.0f / (float)max(deg, 1);
    short8 o;
#pragma unroll
    for (int j = 0; j < 8; ++j) o[j] = (short)f2b(acc[j] * sc);
    *(short8*)(mean + (size_t)node * C + g * 8) = o;
}

// out[node] = z[node] + (1/deg) * sum y[nbr[i]]   (f32 out; z has bias folded)
template<int C>
__global__ __launch_bounds__(256) void gather_add_out_k(
    const unsigned short* __restrict__ y,
    const unsigned short* __restrict__ z,
    const int* __restrict__ cnt,
    const unsigned short* __restrict__ nbr,
    float* __restrict__ out,
    int N)
{
    constexpr int GPN = C / 8;
    constexpr int NPB = 256 / GPN;
    int node = blockIdx.x * NPB + threadIdx.x / GPN;
    int g = threadIdx.x % GPN;
    if (node >= N) return;
    int deg = min(cnt[node], ELL);
    float acc[8] = {};
    ell_row_sum<C>(y, nbr + (size_t)node * ELL, deg, g, acc);
    float sc = 1.0f / (float)max(deg, 1);
    short8 zv = *(const short8*)(z + (size_t)node * C + g * 8);
    float* o = out + (size_t)node * C + g * 8;
    float4 r0, r1;
    r0.x = b2f((unsigned short)zv[0]) + acc[0] * sc;
    r0.y = b2f((unsigned short)zv[1]) + acc[1] * sc;
    r0.z = b2f((unsigned short)zv[2]) + acc[2] * sc;
    r0.w = b2f((unsigned short)zv[3]) + acc[3] * sc;
    r1.x = b2f((unsigned short)zv[4]) + acc[4] * sc;
    r1.y = b2f((unsigned short)zv[5]) + acc[5] * sc;
    r1.z = b2f((unsigned short)zv[6]) + acc[6] * sc;
    r1.w = b2f((unsigned short)zv[7]) + acc[7] * sc;
    *(float4*)o = r0;
    *(float4*)(o + 4) = r1;
}

// Layer-1 fused MFMA GEMM: h = relu( mean@Wt[0] + x@Wt[1] + b1 )
template<int HOUT>
__global__ __launch_bounds__(256) void sage_mfma_l1_k(
    const unsigned short* __restrict__ A0,
    const unsigned short* __restrict__ A1,
    const unsigned short* __restrict__ Wt,
    const float* __restrict__ bias,
    unsigned short* __restrict__ out,
    int N)
{
    constexpr int BM = 128, BN = 64, NF = BN / 16, K1 = 128;
    __shared__ char lds[BN * 256 * 2];           // 32 KB

    const int tid = threadIdx.x;
    const int lane = tid & 63;
    const int w = tid >> 6;
    const int l15 = lane & 15;
    const int lhi = lane >> 4;
    const int bm = blockIdx.x * BM;
    const int bn = blockIdx.y * BN;

    short8 a[2][8];
#pragma unroll
    for (int mf = 0; mf < 2; ++mf) {
        int row = bm + w * 32 + mf * 16 + l15;
        if (row >= N) row = N - 1;
#pragma unroll
        for (int ki = 0; ki < 8; ++ki) {
            const unsigned short* base = (ki < 4) ? A0 : A1;
            a[mf][ki] = *(const short8*)(base + (size_t)row * K1 +
                                         (ki & 3) * 32 + lhi * 8);
        }
    }

#pragma unroll
    for (int i = 0; i < 8; ++i) {
        int u = i * 256 + tid;
        int row = u >> 5, k16 = u & 31;
        int c = k16 >> 4;
        const unsigned short* srcp = Wt + (size_t)c * HOUT * 128 +
                                     (size_t)(bn + row) * 128 + (k16 & 15) * 8;
        short8 v = *(const short8*)srcp;
        *(short8*)(lds + row * 512 + ((k16 ^ (row & 7)) << 4)) = v;
    }
    __syncthreads();

    f32x4 acc[2][NF];
#pragma unroll
    for (int mf = 0; mf < 2; ++mf)
#pragma unroll
        for (int nf = 0; nf < NF; ++nf)
            acc[mf][nf] = (f32x4){0.f, 0.f, 0.f, 0.f};

#pragma unroll
    for (int ki = 0; ki < 8; ++ki) {
        const int k16b = ki * 4 + lhi;
#pragma unroll
        for (int nf = 0; nf < NF; ++nf) {
            int row = nf * 16 + l15;
            short8 b = *(const short8*)(lds + row * 512 +
                                        ((k16b ^ (row & 7)) << 4));
            acc[0][nf] = __builtin_amdgcn_mfma_f32_16x16x32_bf16(a[0][ki], b, acc[0][nf], 0, 0, 0);
            acc[1][nf] = __builtin_amdgcn_mfma_f32_16x16x32_bf16(a[1][ki], b, acc[1][nf], 0, 0, 0);
        }
    }

#pragma unroll
    for (int nf = 0; nf < NF; ++nf) {
        int col = bn + nf * 16 + l15;
        float bv = bias[col];
#pragma unroll
        for (int mf = 0; mf < 2; ++mf) {
#pragma unroll
            for (int r = 0; r < 4; ++r) {
                int row = bm + w * 32 + mf * 16 + lhi * 4 + r;
                if (row < N) {
                    float v = fmaxf(acc[mf][nf][r] + bv, 0.f);
                    out[(size_t)row * HOUT + col] = f2b(v);
                }
            }
        }
    }
}

// Layer-2 dual MFMA GEMM: y = A@W0, z = A@W1 + b2 (both bf16 out).
template<int HOUT>
__global__ __launch_bounds__(256) void dual_mfma_k(
    const unsigned short* __restrict__ A,
    const unsigned short* __restrict__ W0,
    const unsigned short* __restrict__ W1,
    const float* __restrict__ bias,
    unsigned short* __restrict__ y,
    unsigned short* __restrict__ z,
    int N)
{
    constexpr int BM = 128, BN = 32, NF = BN / 16, K1 = 256;
    __shared__ char lds[2 * BN * K1 * 2];        // 32 KB

    const int tid = threadIdx.x;
    const int lane = tid & 63;
    const int w = tid >> 6;
    const int l15 = lane & 15;
    const int lhi = lane >> 4;
    const int bm = blockIdx.x * BM;
    const int bn = blockIdx.y * BN;

    short8 a[2][8];
#pragma unroll
    for (int mf = 0; mf < 2; ++mf) {
        int row = bm + w * 32 + mf * 16 + l15;
        if (row >= N) row = N - 1;
        const unsigned short* ar = A + (size_t)row * K1;
#pragma unroll
        for (int ki = 0; ki < 8; ++ki)
            a[mf][ki] = *(const short8*)(ar + ki * 32 + lhi * 8);
    }

#pragma unroll
    for (int i = 0; i < 8; ++i) {
        int u = i * 256 + tid;                   // < 2048
        int slice = u >> 10;
        int rem = u & 1023;
        int row = rem >> 5, k16 = rem & 31;
        const unsigned short* srcp = (slice ? W1 : W0) +
                                     (size_t)(bn + row) * K1 + k16 * 8;
        short8 v = *(const short8*)srcp;
        *(short8*)(lds + slice * 16384 + row * 512 +
                   ((k16 ^ (row & 7)) << 4)) = v;
    }
    __syncthreads();

    f32x4 accY[2][NF], accZ[2][NF];
#pragma unroll
    for (int mf = 0; mf < 2; ++mf)
#pragma unroll
        for (int nf = 0; nf < NF; ++nf) {
            accY[mf][nf] = (f32x4){0.f, 0.f, 0.f, 0.f};
            accZ[mf][nf] = (f32x4){0.f, 0.f, 0.f, 0.f};
        }

#pragma unroll
    for (int ki = 0; ki < 8; ++ki) {
        const int k16b = ki * 4 + lhi;
#pragma unroll
        for (int nf = 0; nf < NF; ++nf) {
            int row = nf * 16 + l15;
            int off = row * 512 + ((k16b ^ (row & 7)) << 4);
            short8 b0 = *(const short8*)(lds + off);
            short8 b1 = *(const short8*)(lds + 16384 + off);
            accY[0][nf] = __builtin_amdgcn_mfma_f32_16x16x32_bf16(a[0][ki], b0, accY[0][nf], 0, 0, 0);
            accY[1][nf] = __builtin_amdgcn_mfma_f32_16x16x32_bf16(a[1][ki], b0, accY[1][nf], 0, 0, 0);
            accZ[0][nf] = __builtin_amdgcn_mfma_f32_16x16x32_bf16(a[0][ki], b1, accZ[0][nf], 0, 0, 0);
            accZ[1][nf] = __builtin_amdgcn_mfma_f32_16x16x32_bf16(a[1][ki], b1, accZ[1][nf], 0, 0, 0);
        }
    }

#pragma unroll
    for (int nf = 0; nf < NF; ++nf) {
        int col = bn + nf * 16 + l15;
        float bv = bias[col];
#pragma unroll
        for (int mf = 0; mf < 2; ++mf) {
#pragma unroll
            for (int r = 0; r < 4; ++r) {
                int row = bm + w * 32 + mf * 16 + lhi * 4 + r;
                if (row < N) {
                    y[(size_t)row * HOUT + col] = f2b(accY[mf][nf][r]);
                    z[(size_t)row * HOUT + col] = f2b(accZ[mf][nf][r] + bv);
                }
            }
        }
    }
}

extern "C" void kernel_launch(void* const* d_in, const int* in_sizes, int n_in,
                              void* d_out, int out_size, void* d_ws, size_t ws_size,
                              hipStream_t stream) {
    const float* x   = (const float*)d_in[0];
    const int*   ei  = (const int*)d_in[1];
    const float* Wl1 = (const float*)d_in[2];
    const float* Wr1 = (const float*)d_in[3];
    const float* b1  = (const float*)d_in[4];
    const float* Wl2 = (const float*)d_in[5];
    const float* Wr2 = (const float*)d_in[6];
    const float* b2  = (const float*)d_in[7];
    float* out = (float*)d_out;

    const int N = in_sizes[0] / 128;   // 50000
    const int E = in_sizes[1] / 2;     // 600000
    const int* src = ei;
    const int* dst = ei + E;

    // ws layout:
    //   S [N*256 u16]: layer1 mean_bf | layer2 {y_bf, z_bf} (each N*128)
    //   | h_bf [N*256 u16] | x_bf [N*128 u16]
    //   | Wt1 [2*256*128 u16] | Wt2 [2*128*256 u16]
    //   | cnt [N i32] | nbr [N*ELL u16]
    char* ws = (char*)d_ws;
    unsigned short* S       = (unsigned short*)ws;
    unsigned short* mean_bf = S;
    unsigned short* y_bf    = S;
    unsigned short* z_bf    = S + (size_t)N * 128;
    unsigned short* h_bf    = S + (size_t)N * 256;
    unsigned short* x_bf    = h_bf + (size_t)N * 256;
    unsigned short* Wt1     = x_bf + (size_t)N * 128;
    unsigned short* Wt2     = Wt1 + 2 * 256 * 128;
    int*            cnt     = (int*)(Wt2 + 2 * 128 * 256);
    unsigned short* nbr     = (unsigned short*)(cnt + N);

    const int gx = (N + 127) / 128;    // 391

    // ---- prep: x->bf16, weight transpose, zero cnt (one kernel) ----
    long n4 = (long)N * 128 / 4;
    const int nbF2b = (int)((n4 + 255) / 256);       // 6250
    const int nbW   = 512;
    const int nbZ   = (N / 4 + 255) / 256;           // 49
    prep_k<<<nbF2b + nbW + nbZ, 256, 0, stream>>>(
        x, Wl1, Wr1, Wl2, Wr2, x_bf, Wt1, Wt2, cnt, n4, N, nbF2b, nbW);

    // ---- ELL adjacency fill ----
    fill_ell_k<<<(E + 255) / 256, 256, 0, stream>>>(src, dst, cnt, nbr, E);

    // ---- layer 1: mean(x) -> h = relu([mean|x] @ [Wl1;Wr1] + b1) ----
    gather_mean_k<128><<<(N + 15) / 16, 256, 0, stream>>>(
        x_bf, cnt, nbr, mean_bf, N);
    sage_mfma_l1_k<256><<<dim3(gx, 4), 256, 0, stream>>>(
        mean_bf, x_bf, Wt1, b1, h_bf, N);

    // ---- layer 2: {y,z} = h @ {Wl2, Wr2+b2} ; out = z + mean(y) ----
    dual_mfma_k<128><<<dim3(gx, 4), 256, 0, stream>>>(
        h_bf, Wt2, Wt2 + 128 * 256, b2, y_bf, z_bf, N);
    gather_add_out_k<128><<<(N + 15) / 16, 256, 0, stream>>>(
        y_bf, z_bf, cnt, nbr, out, N);
}